// Round 10
// baseline (156.581 us; speedup 1.0000x reference)
//
#include <hip/hip_runtime.h>
#include <math.h>

#define NN 256
#define NS 512
#define MS 32
#define NSTEP 32
#define VRESET 1.0f
#define TAGSH 10

__device__ __forceinline__ float sigf(float x) {
    // fast sigmoid: v_exp_f32 + v_rcp_f32 (~3 ulp); verified no event flips
    // (absmax identical to OCML expf version: 0.125).
    float e = __expf(-x);
    return __builtin_amdgcn_rcpf(1.0f + e);
}

// One RK4 step — op-for-op identical order to the verified kernel.
__device__ __forceinline__ void rk4step(float v, float ii, float s,
                                        float ic, float mu1, float mu2,
                                        float dt, float hh, float h6,
                                        float& vn, float& in_, float& sn)
{
    float kv1 = mu1 * (ii + ic - v);
    float ki1 = -mu2 * ii;
    float ks1 = sigf(v);
    float v2 = v + hh * kv1;
    float i2 = ii + hh * ki1;
    float kv2 = mu1 * (i2 + ic - v2);
    float ki2 = -mu2 * i2;
    float ks2 = sigf(v2);
    float v3 = v + hh * kv2;
    float i3 = ii + hh * ki2;
    float kv3 = mu1 * (i3 + ic - v3);
    float ki3 = -mu2 * i3;
    float ks3 = sigf(v3);
    float v4 = v + dt * kv3;
    float i4 = ii + dt * ki3;
    float kv4 = mu1 * (i4 + ic - v4);
    float ki4 = -mu2 * i4;
    float ks4 = sigf(v4);
    vn  = v  + h6 * (kv1 + 2.0f * kv2 + 2.0f * kv3 + kv4);
    in_ = ii + h6 * (ki1 + 2.0f * ki2 + 2.0f * ki3 + ki4);
    sn  = s  + h6 * (ks1 + 2.0f * ks2 + 2.0f * ks3 + ks4);
}

// R10: ZERO-BARRIER consensus via lag-1 tagged LDS mailboxes.
// Evidence: R6 wall/issue ~20x (barrier machinery dominates); R7 barrier-free
// wall/issue ~3.6x but 4x issue (4 neurons/lane); R9 setprio regressed
// (prioritized wave was latency-stalled). This keeps R6's 4-wave/1-neuron
// issue profile and removes every s_barrier from the main loop.
// Iteration st: compute y_{st+1} (committed on no-cross — R6's spec reuse,
// waste still 1 RK4/event-round), publish flag(st+1) [data -> lgkmcnt(0) ->
// tag], then check flag(st) — published by all waves one RK4 (~200cy) ago,
// so the fast-path read almost never polls. Tags (r*33+st)<<10|meta never
// match stale entries; meta carries (min_crossed_tid<<1)|any like R6.
// ROUND-PARITY double-buffering of mailbox and s_sn/s_sp: clobbering
// round-r data requires a wave 2 rounds ahead, impossible (a wave cannot
// pass round r+1's first poll until all waves exited round r) => deadlock-
// free and race-free by construction, no timing assumptions.
// Event resolve = R6 verbatim (early w-load from meta, redundant per-wave
// argmax, first-max tiebreak); sched_barrier+mem-clobber after tag-confirm
// prevents hoisting resolve LDS reads above the confirm.
// Arithmetic maps 1:1 to R6 => outputs bitwise identical.
__global__ __launch_bounds__(256) void snn_kernel(
    const float* __restrict__ ic_g,     // (256,)
    const float* __restrict__ w,        // (256,256)
    const float* __restrict__ mu,       // (2,)
    const float* __restrict__ v0,       // (256,)
    const float* __restrict__ i0,       // (256,)
    const float* __restrict__ s0,       // (512,256)
    const float* __restrict__ reset_s,  // (32,512,256)
    const int*   __restrict__ t1p,      // scalar
    float* __restrict__ out)
{
    const int tid  = threadIdx.x;   // neuron index
    const int lane = tid & 63;
    const int wid  = tid >> 6;
    const int samp = blockIdx.x;
    const float mu1 = mu[0];
    const float mu2 = mu[1];
    const float t1f = (float)t1p[0];

    __shared__ int4  s_mb[2][NSTEP + 1];              // [round parity][step]
    __shared__ __align__(16) float s_sn[2][2][NN];    // [rpar][step parity]
    __shared__ __align__(16) float s_sp[2][2][NN];

    // zero-init mailboxes (real tag values are >= 1<<TAGSH; 0 never matches)
    {
        int* mf = (int*)s_mb;
        for (int i = tid; i < 2 * (NSTEP + 1) * 4; i += 256) mf[i] = 0;
    }
    __syncthreads();   // once, at kernel start — the only barrier

    float v  = v0[tid];
    float ii = i0[tid];
    float s  = s0[samp * NN + tid];
    const float ic = ic_g[tid];
    float t0 = 0.0f;

    float* times = out;                                  // [NS][MS]
    float* vals  = out + (size_t)NS * MS;                // [NS][MS][NN][3]
    float* marks = out + (size_t)NS * MS * (1 + NN * 3); // [NS][MS][NN]

    for (int r = 0; r < MS; ++r) {
        const int rp = r & 1;
        const int rtag = r * (NSTEP + 1);
        // Prefetch this round's reset row (coalesced 1 KB/block); no barrier
        // anywhere to drain it — stays in flight until the reset.
        const float rs = reset_s[((size_t)r * NS + samp) * NN + tid];

        const float dt = (t1f - t0) / (float)NSTEP;
        float tev = t1f;
        float yv = v, yi = ii, ys = s;
        bool  em = false;
        bool  done = false;
        float wr = 0.0f;

        if (dt != 0.0f) {
            const float hh = 0.5f * dt;
            const float h6 = dt * (1.0f / 6.0f);

            // P = y_{st-1}, C = y_st
            float pv = v, pi_ = ii, ps = s;
            float cv, ci, cs;
            rk4step(pv, pi_, ps, ic, mu1, mu2, dt, hh, h6, cv, ci, cs);
            float t = t0;

            // publish step 1: sn = y1.s, sp = y0.s, then tag
            {
                s_sn[rp][1][tid] = cs;
                s_sp[rp][1][tid] = s;
                unsigned long long bl = __ballot(cs > 0.0f);
                asm volatile("s_waitcnt lgkmcnt(0)" ::: "memory");
                if (lane == 0) {
                    int meta = (bl != 0ull)
                        ? ((((wid << 6) + (int)__builtin_ctzll(bl)) << 1) | 1)
                        : 0;
                    ((volatile int*)&s_mb[rp][1])[wid] =
                        ((rtag + 1) << TAGSH) | meta;
                }
            }

            for (int st = 1; st <= NSTEP; ++st) {
                // 1) early read of this step's mailbox (usually complete)
                int4 f = s_mb[rp][st];

                // 2) compute N = y_{st+1} (committed on no-cross)
                const bool morestep = (st < NSTEP);
                float nv = 0.0f, ni = 0.0f, ns_ = 0.0f;
                if (morestep) {
                    rk4step(cv, ci, cs, ic, mu1, mu2, dt, hh, h6,
                            nv, ni, ns_);
                    // 3) publish step st+1: data -> fence -> tag
                    s_sn[rp][(st + 1) & 1][tid] = ns_;
                    s_sp[rp][(st + 1) & 1][tid] = cs;
                    unsigned long long bl = __ballot(ns_ > 0.0f);
                    asm volatile("s_waitcnt lgkmcnt(0)" ::: "memory");
                    if (lane == 0) {
                        int meta = (bl != 0ull)
                            ? ((((wid << 6) + (int)__builtin_ctzll(bl)) << 1) | 1)
                            : 0;
                        ((volatile int*)&s_mb[rp][st + 1])[wid] =
                            ((rtag + st + 1) << TAGSH) | meta;
                    }
                }

                // 4) confirm step-st tags (lag-1: published one RK4 ago)
                const int want = rtag + st;
                if ((f.x >> TAGSH) != want || (f.y >> TAGSH) != want ||
                    (f.z >> TAGSH) != want || (f.w >> TAGSH) != want) {
                    volatile int* mp = (volatile int*)&s_mb[rp][st];
                    do {
                        __builtin_amdgcn_s_sleep(1);
                        f.x = mp[0]; f.y = mp[1]; f.z = mp[2]; f.w = mp[3];
                    } while ((f.x >> TAGSH) != want || (f.y >> TAGSH) != want ||
                             (f.z >> TAGSH) != want || (f.w >> TAGSH) != want);
                }
                __builtin_amdgcn_sched_barrier(0);
                asm volatile("" ::: "memory");   // confirm -> data reads

                if ((f.x | f.y | f.z | f.w) & 1) {
                    // ---- event at step st: interpolate P <-> C ----
                    const int sp2 = st & 1;
                    const float4 q =
                        *(const float4*)&s_sn[rp][sp2][lane << 2];
                    // eidx from metas; issue w-row load NOW
                    int e0 = (f.x & 1) ? ((f.x >> 1) & 0xFF) : (2 * NN);
                    int e1 = (f.y & 1) ? ((f.y >> 1) & 0xFF) : (2 * NN);
                    int e2 = (f.z & 1) ? ((f.z >> 1) & 0xFF) : (2 * NN);
                    int e3 = (f.w & 1) ? ((f.w >> 1) & 0xFF) : (2 * NN);
                    int ea = e0 < e1 ? e0 : e1;
                    int eb = e2 < e3 ? e2 : e3;
                    int eidx = ea < eb ? ea : eb;
                    wr = w[eidx * NN + tid];

                    // block argmax (redundant identical reduce per wave)
                    unsigned bx = __float_as_uint(q.x);
                    unsigned by = __float_as_uint(q.y);
                    unsigned bz = __float_as_uint(q.z);
                    unsigned bw = __float_as_uint(q.w);
                    unsigned k0 = (bx & 0x80000000u) ? ~bx : (bx | 0x80000000u);
                    unsigned k1 = (by & 0x80000000u) ? ~by : (by | 0x80000000u);
                    unsigned k2 = (bz & 0x80000000u) ? ~bz : (bz | 0x80000000u);
                    unsigned k3 = (bw & 0x80000000u) ? ~bw : (bw | 0x80000000u);
                    unsigned km = k0; int pos = 0;
                    if (k1 > km) { km = k1; pos = 1; }   // strict >: first max
                    if (k2 > km) { km = k2; pos = 2; }
                    if (k3 > km) { km = k3; pos = 3; }
                    unsigned red = km;
#pragma unroll
                    for (int off = 32; off >= 1; off >>= 1) {
                        unsigned o = __shfl_xor(red, off);
                        red = (o > red) ? o : red;
                    }
                    unsigned long long cm = __ballot(km == red);
                    int L = (int)__builtin_ctzll(cm);        // lowest lane
                    int wpos = __builtin_amdgcn_readlane(pos, L);
                    int bn = (L << 2) + wpos;                // first-max idx

                    float bv  = s_sn[rp][sp2][bn];
                    float bsp = s_sp[rp][sp2][bn];
                    float frac = bsp / (bsp - bv + 1e-12f);
                    frac = fminf(fmaxf(frac, 0.0f), 1.0f);
                    tev = t + frac * dt;                     // t = t(P)
                    yv = pv  + frac * (cv - pv);
                    yi = pi_ + frac * (ci - pi_);
                    ys = ps  + frac * (cs - ps);
                    em = (cs > 0.0f);
                    done = true;
                    break;
                }

                // 5) advance pipeline
                if (morestep) {
                    pv = cv; pi_ = ci; ps = cs;
                    cv = nv; ci = ni; cs = ns_;
                    t += dt;
                }
            }

            if (!done) { yv = cv; yi = ci; ys = cs; }  // y_32, no event
        }

        // ---- emit round outputs ----
        const int sr = samp * MS + r;
        if (tid == 0) times[sr] = tev;
        {
            float* p = vals + ((size_t)sr * NN + tid) * 3;
            p[0] = yv;
            p[1] = yi;
            p[2] = ys;
            marks[(size_t)sr * NN + tid] = em ? 1.0f : 0.0f;
        }

        // ---- reset for next round ----
        if (done) {
            v  = yv - (em ? VRESET : 0.0f);
            ii = yi + wr;
            float sres = em ? rs : ys;
            s = fminf(sres, 0.0f);
        } else {
            v = yv; ii = yi;
            s = fminf(ys, 0.0f);
        }
        t0 = tev;
    }
}

extern "C" void kernel_launch(void* const* d_in, const int* in_sizes, int n_in,
                              void* d_out, int out_size, void* d_ws, size_t ws_size,
                              hipStream_t stream) {
    const float* ic      = (const float*)d_in[0];
    const float* w       = (const float*)d_in[1];
    const float* mu      = (const float*)d_in[2];
    const float* v0      = (const float*)d_in[3];
    const float* i0      = (const float*)d_in[4];
    const float* s0      = (const float*)d_in[5];
    const float* reset_s = (const float*)d_in[6];
    const int*   t1p     = (const int*)d_in[7];
    float* out = (float*)d_out;

    snn_kernel<<<dim3(NS), dim3(256), 0, stream>>>(ic, w, mu, v0, i0, s0,
                                                   reset_s, t1p, out);
}

// Round 11
// 137.992 us; speedup vs baseline: 1.1347x; 1.1347x over previous
//
#include <hip/hip_runtime.h>
#include <math.h>

#define NN 256
#define NS 512
#define MS 32
#define NSTEP 32
#define VRESET 1.0f

__device__ __forceinline__ float sigf(float x) {
    // fast sigmoid: v_exp_f32 + v_rcp_f32 (~3 ulp); verified no event flips
    // (absmax identical to OCML expf version: 0.125).
    float e = __expf(-x);
    return __builtin_amdgcn_rcpf(1.0f + e);
}

// Barrier WITHOUT the vmcnt(0) drain that __syncthreads() emits.
// LDS-only visibility; global stores/loads deliberately stay in flight.
__device__ __forceinline__ void block_sync_lds() {
    asm volatile("s_waitcnt lgkmcnt(0)" ::: "memory");
    __builtin_amdgcn_s_barrier();
    asm volatile("" ::: "memory");
}

// One RK4 step — op-for-op identical order to the verified kernel.
__device__ __forceinline__ void rk4step(float v, float ii, float s,
                                        float ic, float mu1, float mu2,
                                        float dt, float hh, float h6,
                                        float& vn, float& in_, float& sn)
{
    float kv1 = mu1 * (ii + ic - v);
    float ki1 = -mu2 * ii;
    float ks1 = sigf(v);
    float v2 = v + hh * kv1;
    float i2 = ii + hh * ki1;
    float kv2 = mu1 * (i2 + ic - v2);
    float ki2 = -mu2 * i2;
    float ks2 = sigf(v2);
    float v3 = v + hh * kv2;
    float i3 = ii + hh * ki2;
    float kv3 = mu1 * (i3 + ic - v3);
    float ki3 = -mu2 * i3;
    float ks3 = sigf(v3);
    float v4 = v + dt * kv3;
    float i4 = ii + dt * ki3;
    float kv4 = mu1 * (i4 + ic - v4);
    float ki4 = -mu2 * i4;
    float ks4 = sigf(v4);
    vn  = v  + h6 * (kv1 + 2.0f * kv2 + 2.0f * kv3 + kv4);
    in_ = ii + h6 * (ki1 + 2.0f * ki2 + 2.0f * ki3 + ki4);
    sn  = s  + h6 * (ks1 + 2.0f * ks2 + 2.0f * ks3 + ks4);
}

// One block (256 threads = 4 waves) per sample; thread tid owns neuron tid.
// R11 = R6 champion (52-57us; barriers exonerated by R7/R10 — both
// barrier-free schemes lost; rounds cross at step ~1 per R2/R4 issue-cycle
// algebra, so the event path runs EVERY round) with the argmax moved
// PRE-BARRIER, where its latency overlaps the convoy:
//  - at iteration top each wave reduces its own 64 cs values (6x 32-bit
//    shfl_xor max butterfly + ballot(key==max)+ctz + 2 shfl for the
//    winner's cs/ps); lane0 publishes ONE int4 per wave:
//    {wave_max_key, meta(min_crossed_tid<<1|any), winner_ps, winner_cs}.
//  - post-barrier resolve = 4 broadcast b128 reads (latency covered by the
//    spec k3/k4) + 3 unsigned compares + frac — replaces R6's 400-500cy
//    chain (float4 LDS read -> key map -> 6-level butterfly -> ballot/
//    readlane -> 2 dependent LDS reads).
//  - per-thread s_sn/s_sp publishes GONE (less pre-barrier lgkmcnt drain;
//    LDS 4.6KB -> 256B).
// Tiebreaks exact: in-wave ctz = lowest lane; cross-wave ascending strict->
// merge = lowest wave => lowest global tid among equal maxima (= reference
// first-max argmax). Winner cs/ps are the identical values => outputs
// bitwise identical. No setprio (R9 regressed), no rs-ahead (R9 neutral).
__global__ __launch_bounds__(256) void snn_kernel(
    const float* __restrict__ ic_g,     // (256,)
    const float* __restrict__ w,        // (256,256)
    const float* __restrict__ mu,       // (2,)
    const float* __restrict__ v0,       // (256,)
    const float* __restrict__ i0,       // (256,)
    const float* __restrict__ s0,       // (512,256)
    const float* __restrict__ reset_s,  // (32,512,256)
    const int*   __restrict__ t1p,      // scalar
    float* __restrict__ out)
{
    const int tid  = threadIdx.x;   // neuron index
    const int lane = tid & 63;
    const int wid  = tid >> 6;
    const int samp = blockIdx.x;
    const float mu1 = mu[0];
    const float mu2 = mu[1];
    const float t1f = (float)t1p[0];

    __shared__ int4 s_flag[4][4];   // [st&3][wave]: key, meta, ps, cs

    float v  = v0[tid];
    float ii = i0[tid];
    float s  = s0[samp * NN + tid];
    const float ic = ic_g[tid];
    float t0 = 0.0f;

    float* times = out;                                  // [NS][MS]
    float* vals  = out + (size_t)NS * MS;                // [NS][MS][NN][3]
    float* marks = out + (size_t)NS * MS * (1 + NN * 3); // [NS][MS][NN]

    for (int r = 0; r < MS; ++r) {
        // Prefetch this round's reset row (coalesced 1 KB/block); raw
        // barriers keep it in flight until the reset.
        const float rs = reset_s[((size_t)r * NS + samp) * NN + tid];

        const float dt = (t1f - t0) / (float)NSTEP;
        float tev = t1f;
        float yv = v, yi = ii, ys = s;
        bool  em = false;
        bool  done = false;
        float wr = 0.0f;

        if (dt != 0.0f) {
            const float hh = 0.5f * dt;
            const float h6 = dt * (1.0f / 6.0f);

            // pipeline: P = y_st, C = y_{st+1}
            float pv = v, pi_ = ii, ps = s;
            float cv, ci, cs;
            rk4step(pv, pi_, ps, ic, mu1, mu2, dt, hh, h6, cv, ci, cs);
            float t = t0;

            for (int st = 0; st < NSTEP; ++st) {
                // 1) PRE-BARRIER wave-local event summary of step st.
                //    Butterfly latency overlaps the convoy + other block.
                unsigned long long bl = __ballot(cs > 0.0f);
                unsigned csb  = __float_as_uint(cs);
                unsigned okey = (csb & 0x80000000u) ? ~csb
                                                    : (csb | 0x80000000u);
                unsigned red = okey;
#pragma unroll
                for (int off = 32; off >= 1; off >>= 1) {
                    unsigned o = __shfl_xor(red, off);
                    red = (o > red) ? o : red;
                }
                unsigned long long wm = __ballot(okey == red);
                int   winlane = (int)__builtin_ctzll(wm);  // lowest lane
                float wps = __shfl(ps, winlane);           // winner's s_prev
                float wcs = __shfl(cs, winlane);           // winner's s_new
                if (lane == 0) {
                    int mincross = (bl != 0ull)
                        ? ((wid << 6) + (int)__builtin_ctzll(bl)) : 0x1FF;
                    int4 e;
                    e.x = (int)red;
                    e.y = (mincross << 1) | ((bl != 0ull) ? 1 : 0);
                    e.z = __float_as_int(wps);
                    e.w = __float_as_int(wcs);
                    s_flag[st & 3][wid] = e;
                }

                // 2a) spec y_{st+2} first half — covers ds_write drain+barrier
                float kv1 = mu1 * (ci + ic - cv);
                float ki1 = -mu2 * ci;
                float ks1 = sigf(cv);
                float v2 = cv + hh * kv1;
                float i2 = ci + hh * ki1;
                float kv2 = mu1 * (i2 + ic - v2);
                float ki2 = -mu2 * i2;
                float ks2 = sigf(v2);

                __builtin_amdgcn_sched_barrier(0);
                block_sync_lds();
                __builtin_amdgcn_sched_barrier(0);

                // 3) 4 broadcast b128 reads of the wave summaries...
                int4 f0 = s_flag[st & 3][0];
                int4 f1 = s_flag[st & 3][1];
                int4 f2 = s_flag[st & 3][2];
                int4 f3 = s_flag[st & 3][3];

                // 2b) ...latency covered by spec second half
                float v3 = cv + hh * kv2;
                float i3 = ci + hh * ki2;
                float kv3 = mu1 * (i3 + ic - v3);
                float ki3 = -mu2 * i3;
                float ks3 = sigf(v3);
                float v4 = cv + dt * kv3;
                float i4 = ci + dt * ki3;
                float kv4 = mu1 * (i4 + ic - v4);
                float ki4 = -mu2 * i4;
                float ks4 = sigf(v4);
                float nv  = cv + h6 * (kv1 + 2.0f * kv2 + 2.0f * kv3 + kv4);
                float ni  = ci + h6 * (ki1 + 2.0f * ki2 + 2.0f * ki3 + ki4);
                float ns_ = cs + h6 * (ks1 + 2.0f * ks2 + 2.0f * ks3 + ks4);

                if ((f0.y | f1.y | f2.y | f3.y) & 1) {
                    // ---- event at step st ----
                    // eidx = min crossed tid from metas; issue w-load NOW
                    int e0 = (f0.y & 1) ? ((f0.y >> 1) & 0x1FF) : 512;
                    int e1 = (f1.y & 1) ? ((f1.y >> 1) & 0x1FF) : 512;
                    int e2 = (f2.y & 1) ? ((f2.y >> 1) & 0x1FF) : 512;
                    int e3 = (f3.y & 1) ? ((f3.y >> 1) & 0x1FF) : 512;
                    int ea = e0 < e1 ? e0 : e1;
                    int eb = e2 < e3 ? e2 : e3;
                    int eidx = ea < eb ? ea : eb;
                    wr = w[eidx * NN + tid];

                    // cross-wave argmax merge: ascending waves, strict > —
                    // lowest wave wins ties => lowest global tid overall
                    unsigned bk = (unsigned)f0.x;
                    float bsp = __int_as_float(f0.z);
                    float bv  = __int_as_float(f0.w);
                    if ((unsigned)f1.x > bk) { bk = (unsigned)f1.x;
                        bsp = __int_as_float(f1.z); bv = __int_as_float(f1.w); }
                    if ((unsigned)f2.x > bk) { bk = (unsigned)f2.x;
                        bsp = __int_as_float(f2.z); bv = __int_as_float(f2.w); }
                    if ((unsigned)f3.x > bk) { bk = (unsigned)f3.x;
                        bsp = __int_as_float(f3.z); bv = __int_as_float(f3.w); }

                    float frac = bsp / (bsp - bv + 1e-12f);
                    frac = fminf(fmaxf(frac, 0.0f), 1.0f);
                    tev = t + frac * dt;
                    yv = pv  + frac * (cv - pv);
                    yi = pi_ + frac * (ci - pi_);
                    ys = ps  + frac * (cs - ps);
                    em = (cs > 0.0f);
                    done = true;
                    break;
                }

                // 4) advance pipeline (guarded: no-event rounds end at y_32)
                if (st + 1 < NSTEP) {
                    pv = cv; pi_ = ci; ps = cs;
                    cv = nv; ci = ni; cs = ns_;
                    t += dt;
                }
            }

            if (!done) { yv = cv; yi = ci; ys = cs; }  // y_32, no event
        }

        // ---- emit round outputs (stores stay in flight across barriers) ----
        const int sr = samp * MS + r;
        if (tid == 0) times[sr] = tev;
        {
            float* p = vals + ((size_t)sr * NN + tid) * 3;
            p[0] = yv;
            p[1] = yi;
            p[2] = ys;
            marks[(size_t)sr * NN + tid] = em ? 1.0f : 0.0f;
        }

        // ---- reset for next round ----
        if (done) {
            v  = yv - (em ? VRESET : 0.0f);
            ii = yi + wr;
            float sres = em ? rs : ys;
            s = fminf(sres, 0.0f);
        } else {
            v = yv; ii = yi;
            s = fminf(ys, 0.0f);
        }
        t0 = tev;
    }
}

extern "C" void kernel_launch(void* const* d_in, const int* in_sizes, int n_in,
                              void* d_out, int out_size, void* d_ws, size_t ws_size,
                              hipStream_t stream) {
    const float* ic      = (const float*)d_in[0];
    const float* w       = (const float*)d_in[1];
    const float* mu      = (const float*)d_in[2];
    const float* v0      = (const float*)d_in[3];
    const float* i0      = (const float*)d_in[4];
    const float* s0      = (const float*)d_in[5];
    const float* reset_s = (const float*)d_in[6];
    const int*   t1p     = (const int*)d_in[7];
    float* out = (float*)d_out;

    snn_kernel<<<dim3(NS), dim3(256), 0, stream>>>(ic, w, mu, v0, i0, s0,
                                                   reset_s, t1p, out);
}

// Round 12
// 134.012 us; speedup vs baseline: 1.1684x; 1.0297x over previous
//
#include <hip/hip_runtime.h>
#include <math.h>

#define NN 256
#define NS 512
#define MS 32
#define NSTEP 32
#define VRESET 1.0f

__device__ __forceinline__ float sigf(float x) {
    // fast sigmoid: v_exp_f32 + v_rcp_f32 (~3 ulp); verified no event flips
    // (absmax identical to OCML expf version: 0.125).
    float e = __expf(-x);
    return __builtin_amdgcn_rcpf(1.0f + e);
}

// Barrier WITHOUT the vmcnt(0) drain that __syncthreads() emits.
// LDS-only visibility; global stores/loads deliberately stay in flight.
__device__ __forceinline__ void block_sync_lds() {
    asm volatile("s_waitcnt lgkmcnt(0)" ::: "memory");
    __builtin_amdgcn_s_barrier();
    asm volatile("" ::: "memory");
}

// One RK4 step — op-for-op identical order to the verified kernel.
__device__ __forceinline__ void rk4step(float v, float ii, float s,
                                        float ic, float mu1, float mu2,
                                        float dt, float hh, float h6,
                                        float& vn, float& in_, float& sn)
{
    float kv1 = mu1 * (ii + ic - v);
    float ki1 = -mu2 * ii;
    float ks1 = sigf(v);
    float v2 = v + hh * kv1;
    float i2 = ii + hh * ki1;
    float kv2 = mu1 * (i2 + ic - v2);
    float ki2 = -mu2 * i2;
    float ks2 = sigf(v2);
    float v3 = v + hh * kv2;
    float i3 = ii + hh * ki2;
    float kv3 = mu1 * (i3 + ic - v3);
    float ki3 = -mu2 * i3;
    float ks3 = sigf(v3);
    float v4 = v + dt * kv3;
    float i4 = ii + dt * ki3;
    float kv4 = mu1 * (i4 + ic - v4);
    float ki4 = -mu2 * i4;
    float ks4 = sigf(v4);
    vn  = v  + h6 * (kv1 + 2.0f * kv2 + 2.0f * kv3 + kv4);
    in_ = ii + h6 * (ki1 + 2.0f * ki2 + 2.0f * ki3 + ki4);
    sn  = s  + h6 * (ks1 + 2.0f * ks2 + 2.0f * ks3 + ks4);
}

// Wave-local event summary of one step (cur = s_new, prev = s_prev):
// lane0 publishes int4 {wave_max_ordered_key, (min_crossed_tid<<1)|any,
// winner_ps_bits, winner_cs_bits}. Tiebreaks: in-wave ctz = lowest lane;
// cross-wave ascending strict-> merge (in resolve) = lowest wave => exact
// reference first-max argmax.
__device__ __forceinline__ void publish_summary(float curS, float prevS,
                                                int lane, int wid,
                                                int4* slotp)
{
    unsigned long long bl = __ballot(curS > 0.0f);
    unsigned b = __float_as_uint(curS);
    unsigned okey = (b & 0x80000000u) ? ~b : (b | 0x80000000u);
    unsigned red = okey;
#pragma unroll
    for (int off = 32; off >= 1; off >>= 1) {
        unsigned o = __shfl_xor(red, off);
        red = (o > red) ? o : red;
    }
    unsigned long long wm = __ballot(okey == red);
    int   winlane = (int)__builtin_ctzll(wm);
    float wps = __shfl(prevS, winlane);
    float wcs = __shfl(curS, winlane);
    if (lane == 0) {
        int mincross = (bl != 0ull)
            ? ((wid << 6) + (int)__builtin_ctzll(bl)) : 0x1FF;
        int4 e;
        e.x = (int)red;
        e.y = (mincross << 1) | ((bl != 0ull) ? 1 : 0);
        e.z = __float_as_int(wps);
        e.w = __float_as_int(wcs);
        slotp[wid] = e;
    }
}

// One block (256 threads = 4 waves) per sample; thread tid owns neuron tid.
// R12 = R11 with the flag read SOFTWARE-PIPELINED across the barrier and the
// event check moved PRE-barrier. Ledger: barriers exonerated (R7/R10 lost),
// resolve exonerated (R11 neutral), round-boundary loads exonerated (R9),
// speculative-work reduction lost (R4/R5). Remaining wall = per-iteration
// skeleton: RK4 chain + exposed post-barrier ds_read (~120cy, m117) +
// convoy. This version:
//  - flag[st] read issued immediately AFTER barrier(st-1) -> one full RK4
//    of cover; latency off the chain.
//  - check flag[st] BEFORE publishing flag[st+1]: event rounds end at
//    RK4 -> check -> in-register resolve, skipping the final barrier and
//    all post-barrier LDS latency.
//  - no-event path: summary(C) -> publish flag[st+1] -> barrier -> issue
//    next read -> rotate. RK4s/round = k+1 (same as R6); k=1 rounds have
//    exactly 1 barrier (same as R6).
//  - sched_barrier(0) pins RK4-before-check (compiler would otherwise sink
//    the RK4 below the branch, re-exposing the read — rule #18 analog).
//  - WAR on the 4-slot ring is barrier-proven; prologue slot alternates by
//    round parity (slots 4/5) so cross-round reuse is barrier-separated.
// Values/tiebreaks/t-accumulation map 1:1 to R6/R11 => bitwise identical.
__global__ __launch_bounds__(256) void snn_kernel(
    const float* __restrict__ ic_g,     // (256,)
    const float* __restrict__ w,        // (256,256)
    const float* __restrict__ mu,       // (2,)
    const float* __restrict__ v0,       // (256,)
    const float* __restrict__ i0,       // (256,)
    const float* __restrict__ s0,       // (512,256)
    const float* __restrict__ reset_s,  // (32,512,256)
    const int*   __restrict__ t1p,      // scalar
    float* __restrict__ out)
{
    const int tid  = threadIdx.x;   // neuron index
    const int lane = tid & 63;
    const int wid  = tid >> 6;
    const int samp = blockIdx.x;
    const float mu1 = mu[0];
    const float mu2 = mu[1];
    const float t1f = (float)t1p[0];

    __shared__ int4 s_flag[6][4];   // slots 0..3: in-loop ring; 4,5: prologue

    float v  = v0[tid];
    float ii = i0[tid];
    float s  = s0[samp * NN + tid];
    const float ic = ic_g[tid];
    float t0 = 0.0f;

    float* times = out;                                  // [NS][MS]
    float* vals  = out + (size_t)NS * MS;                // [NS][MS][NN][3]
    float* marks = out + (size_t)NS * MS * (1 + NN * 3); // [NS][MS][NN]

    for (int r = 0; r < MS; ++r) {
        // Prefetch this round's reset row (coalesced 1 KB/block); raw
        // barriers keep it in flight until the reset.
        const float rs = reset_s[((size_t)r * NS + samp) * NN + tid];

        const float dt = (t1f - t0) / (float)NSTEP;
        float tev = t1f;
        float yv = v, yi = ii, ys = s;
        bool  em = false;
        bool  done = false;
        float wr = 0.0f;

        if (dt != 0.0f) {
            const float hh = 0.5f * dt;
            const float h6 = dt * (1.0f / 6.0f);

            // A = y_{st-1}, B = y_st (committed pair for interpolation)
            float Av = v, Ai = ii, As = s;
            float Bv, Bi, Bs;
            rk4step(Av, Ai, As, ic, mu1, mu2, dt, hh, h6, Bv, Bi, Bs);

            // prologue: summary of step 1 (cur=y1, prev=y0), parity slot
            publish_summary(Bs, As, lane, wid, s_flag[4 + (r & 1)]);
            block_sync_lds();
            int4 p0 = s_flag[4 + (r & 1)][0];
            int4 p1 = s_flag[4 + (r & 1)][1];
            int4 p2 = s_flag[4 + (r & 1)][2];
            int4 p3 = s_flag[4 + (r & 1)][3];
            __builtin_amdgcn_sched_barrier(0);

            float t = t0;                     // time of A
            float Cv, Ci, Cs;

            for (int st = 1; st < NSTEP; ++st) {
                // compute y_{st+1}; covers the pending flag[st] read latency
                rk4step(Bv, Bi, Bs, ic, mu1, mu2, dt, hh, h6, Cv, Ci, Cs);
                __builtin_amdgcn_sched_barrier(0);

                if ((p0.y | p1.y | p2.y | p3.y) & 1) {
                    done = true;              // event at step st: P=A, C=B
                    break;
                }

                // no event: summary of step st+1, publish, barrier, next read
                publish_summary(Cs, Bs, lane, wid, s_flag[(st + 1) & 3]);
                block_sync_lds();
                p0 = s_flag[(st + 1) & 3][0];
                p1 = s_flag[(st + 1) & 3][1];
                p2 = s_flag[(st + 1) & 3][2];
                p3 = s_flag[(st + 1) & 3][3];
                __builtin_amdgcn_sched_barrier(0);

                Av = Bv; Ai = Bi; As = Bs;    // rotate: A=y_st, B=y_{st+1}
                Bv = Cv; Bi = Ci; Bs = Cs;
                t += dt;
            }

            if (!done) {
                // loop exhausted: A=y31, B=y32, pending flags = flag[32]
                if ((p0.y | p1.y | p2.y | p3.y) & 1) done = true;
                else { yv = Bv; yi = Bi; ys = Bs; }   // y_32, no event
            }

            if (done) {
                // ---- event resolve, all inputs already in registers ----
                int e0 = (p0.y & 1) ? ((p0.y >> 1) & 0x1FF) : 512;
                int e1 = (p1.y & 1) ? ((p1.y >> 1) & 0x1FF) : 512;
                int e2 = (p2.y & 1) ? ((p2.y >> 1) & 0x1FF) : 512;
                int e3 = (p3.y & 1) ? ((p3.y >> 1) & 0x1FF) : 512;
                int ea = e0 < e1 ? e0 : e1;
                int eb = e2 < e3 ? e2 : e3;
                int eidx = ea < eb ? ea : eb;
                wr = w[eidx * NN + tid];      // L2 latency hides under merge

                unsigned bk = (unsigned)p0.x;
                float bsp = __int_as_float(p0.z);
                float bv  = __int_as_float(p0.w);
                if ((unsigned)p1.x > bk) { bk = (unsigned)p1.x;
                    bsp = __int_as_float(p1.z); bv = __int_as_float(p1.w); }
                if ((unsigned)p2.x > bk) { bk = (unsigned)p2.x;
                    bsp = __int_as_float(p2.z); bv = __int_as_float(p2.w); }
                if ((unsigned)p3.x > bk) { bk = (unsigned)p3.x;
                    bsp = __int_as_float(p3.z); bv = __int_as_float(p3.w); }

                float frac = bsp / (bsp - bv + 1e-12f);
                frac = fminf(fmaxf(frac, 0.0f), 1.0f);
                tev = t + frac * dt;
                yv = Av + frac * (Bv - Av);
                yi = Ai + frac * (Bi - Ai);
                ys = As + frac * (Bs - As);
                em = (Bs > 0.0f);
            }
        }

        // ---- emit round outputs (stores stay in flight across barriers) ----
        const int sr = samp * MS + r;
        if (tid == 0) times[sr] = tev;
        {
            float* p = vals + ((size_t)sr * NN + tid) * 3;
            p[0] = yv;
            p[1] = yi;
            p[2] = ys;
            marks[(size_t)sr * NN + tid] = em ? 1.0f : 0.0f;
        }

        // ---- reset for next round ----
        if (done) {
            v  = yv - (em ? VRESET : 0.0f);
            ii = yi + wr;
            float sres = em ? rs : ys;
            s = fminf(sres, 0.0f);
        } else {
            v = yv; ii = yi;
            s = fminf(ys, 0.0f);
        }
        t0 = tev;
    }
}

extern "C" void kernel_launch(void* const* d_in, const int* in_sizes, int n_in,
                              void* d_out, int out_size, void* d_ws, size_t ws_size,
                              hipStream_t stream) {
    const float* ic      = (const float*)d_in[0];
    const float* w       = (const float*)d_in[1];
    const float* mu      = (const float*)d_in[2];
    const float* v0      = (const float*)d_in[3];
    const float* i0      = (const float*)d_in[4];
    const float* s0      = (const float*)d_in[5];
    const float* reset_s = (const float*)d_in[6];
    const int*   t1p     = (const int*)d_in[7];
    float* out = (float*)d_out;

    snn_kernel<<<dim3(NS), dim3(256), 0, stream>>>(ic, w, mu, v0, i0, s0,
                                                   reset_s, t1p, out);
}